// Round 10
// baseline (555.844 us; speedup 1.0000x reference)
//
#include <hip/hip_runtime.h>

typedef unsigned short u16;
typedef __attribute__((ext_vector_type(8))) short bf16x8;
typedef __attribute__((ext_vector_type(4))) float f32x4;
typedef __attribute__((ext_vector_type(8))) unsigned short u16x8;
typedef __attribute__((ext_vector_type(4))) unsigned short u16x4;

__device__ __forceinline__ u16 f2bf(float f){
  unsigned int u = __builtin_bit_cast(unsigned int, f);
  u += 0x7FFFu + ((u >> 16) & 1u);
  return (u16)(u >> 16);
}
__device__ __forceinline__ float bf2f(u16 h){
  unsigned int u = ((unsigned int)h) << 16;
  return __builtin_bit_cast(float, u);
}

__device__ __forceinline__ void load16(const u16* g, u16* s){
  __builtin_amdgcn_global_load_lds((const __attribute__((address_space(1))) unsigned int*)g,
                                   (__attribute__((address_space(3))) unsigned int*)s,
                                   16, 0, 0);
}

// From R: S = 0.5(A-A^T). Sbf = bf16(S); Dbf = bf16((c+1)(cI - S)), c=1.000001
__global__ __launch_bounds__(256) void build_s(const float* __restrict__ R, u16* __restrict__ Sbf,
                                               u16* __restrict__ Dbf){
  int idx = blockIdx.x * 256 + threadIdx.x;
  int b = idx >> 18;
  int i = (idx >> 9) & 511;
  int j = idx & 511;
  float a  = R[idx];
  float at = R[(b << 18) + (j << 9) + i];
  float s = 0.5f * (a - at);
  Sbf[idx] = f2bf(s);
  Dbf[idx] = f2bf((i == j ? 2.000003f : 0.0f) - 2.000001f * s);
}

// vectorized f32 -> bf16 (8 elems / thread, exact multiple)
__global__ __launch_bounds__(256) void conv_bf16(const float* __restrict__ src, u16* __restrict__ dst){
  size_t i = (size_t)blockIdx.x * 256 + threadIdx.x;
  const float4* s = (const float4*)src + i * 2;
  float4 v0 = s[0], v1 = s[1];
  u16x8 o = { f2bf(v0.x), f2bf(v0.y), f2bf(v0.z), f2bf(v0.w),
              f2bf(v1.x), f2bf(v1.y), f2bf(v1.z), f2bf(v1.w) };
  *(u16x8*)(dst + i * 8) = o;
}

// Wt[b][i][j] = W[b*512 + j][i]  (bf16), i in [0,4096), j in [0,512)
__global__ __launch_bounds__(256) void transpose_w(const float* __restrict__ W, u16* __restrict__ Wt){
  const int b = blockIdx.z;
  const int i0 = blockIdx.x << 5;
  const int j0 = blockIdx.y << 5;
  __shared__ float tile[32][33];
  const int t = threadIdx.x;
  const int r = t >> 3, c = (t & 7) << 2;
  float4 v = *(const float4*)&W[(size_t)((b << 9) + j0 + r) * 4096 + i0 + c];
  tile[r][c+0] = v.x; tile[r][c+1] = v.y; tile[r][c+2] = v.z; tile[r][c+3] = v.w;
  __syncthreads();
  u16x4 o = { f2bf(tile[c+0][r]), f2bf(tile[c+1][r]), f2bf(tile[c+2][r]), f2bf(tile[c+3][r]) };
  *(u16x4*)&Wt[((size_t)b << 21) + (size_t)(i0 + r) * 512 + j0 + c] = o;
}

// 128x128-tile bt-form bf16 MFMA gemm (m97 structure, PROVEN rounds 1-9):
// C[m,n] = sum_k A[m,k]*B[n,k], batched over blockIdx.z.
// EPI 3:  bf16 C = 2*diag - acc
// EPI 6:  bf16 C = bf16(aux_u16[gi]) + acc
// EPI 7:  bf16 C = acc ; also dup into aux (width 1024) at [row][col], [row][col+512]
// EPI 9:  bf16 C = acc - diag
// EPI 10: bf16 C = diag - acc
// EPI 11: p = acc + c^2*diag (f32): Cout(width1024)=[bf16(p)|bf16(p-ph)];
//         x1 = bf16(2b*diag - b^2*p) -> aux (width 512) and aux2 (width 1024, dup)
template<int EPI>
__global__ __launch_bounds__(256) void gemm_bt(const u16* __restrict__ A, const u16* __restrict__ B,
                                               void* __restrict__ Cout, const void* __restrict__ aux,
                                               void* __restrict__ aux2,
                                               int M, int N, int K){
  const int bz = blockIdx.z;
  const u16* Ab = A + (size_t)bz * M * K;
  const u16* Bb = B + (size_t)bz * N * K;
  const int m0 = blockIdx.y << 7, n0 = blockIdx.x << 7;
  __shared__ __align__(16) u16 As[4096];
  __shared__ __align__(16) u16 Bs[4096];
  const int t = threadIdx.x;
  const int w = t >> 6, l = t & 63;
  const int wr = w >> 1, wc = w & 1;
  const int kofs = (l & 3) << 3;
  const int rA = l >> 2;
  const int aRd = ((wr << 6) + (l & 15)) * 32 + ((l >> 4) << 3);
  const int bRd = ((wc << 6) + (l & 15)) * 32 + ((l >> 4) << 3);
  f32x4 acc[4][4] = {};
  for (int k0 = 0; k0 < K; k0 += 32){
#pragma unroll
    for (int j = 0; j < 2; ++j){
      int rowBase = ((w << 1) + j) << 4;
      load16(&Ab[(size_t)(m0 + rowBase + rA) * K + k0 + kofs], &As[((w << 1) + j) << 9]);
      load16(&Bb[(size_t)(n0 + rowBase + rA) * K + k0 + kofs], &Bs[((w << 1) + j) << 9]);
    }
    __syncthreads();
    bf16x8 aF[4], bF[4];
#pragma unroll
    for (int mf = 0; mf < 4; ++mf) aF[mf] = *(const bf16x8*)&As[aRd + (mf << 9)];
#pragma unroll
    for (int nf = 0; nf < 4; ++nf) bF[nf] = *(const bf16x8*)&Bs[bRd + (nf << 9)];
#pragma unroll
    for (int mf = 0; mf < 4; ++mf)
#pragma unroll
      for (int nf = 0; nf < 4; ++nf)
        acc[mf][nf] = __builtin_amdgcn_mfma_f32_16x16x32_bf16(aF[mf], bF[nf], acc[mf][nf], 0, 0, 0);
    __syncthreads();
  }
#pragma unroll
  for (int mf = 0; mf < 4; ++mf){
#pragma unroll
    for (int nf = 0; nf < 4; ++nf){
      const int col = n0 + (wc << 6) + (nf << 4) + (l & 15);
#pragma unroll
      for (int q = 0; q < 4; ++q){
        const int row = m0 + (wr << 6) + (mf << 4) + ((l >> 4) << 2) + q;
        float v = acc[mf][nf][q];
        size_t gi = ((size_t)bz * M + row) * N + col;
        size_t g2 = (((size_t)bz * M + row) << 10) + col;
        if (EPI == 3){
          ((u16*)Cout)[gi] = f2bf((row == col ? 2.0f : 0.0f) - v);
        } else if (EPI == 6){
          ((u16*)Cout)[gi] = f2bf(bf2f(((const u16*)aux)[gi]) + v);
        } else if (EPI == 7){
          u16 o = f2bf(v);
          ((u16*)Cout)[gi] = o;
          u16* d = (u16*)const_cast<void*>(aux);
          d[g2] = o;
          d[g2 + 512] = o;
        } else if (EPI == 9){
          ((u16*)Cout)[gi] = f2bf(v - (row == col ? 1.0f : 0.0f));
        } else if (EPI == 10){
          ((u16*)Cout)[gi] = f2bf((row == col ? 1.0f : 0.0f) - v);
        } else {  // EPI 11: fused P-split + closed-form first NS iterate
          float p = v + (row == col ? 1.000002f : 0.0f);
          u16 ph = f2bf(p);
          ((u16*)Cout)[g2] = ph;
          ((u16*)Cout)[g2 + 512] = f2bf(p - bf2f(ph));
          const float beta = 0.8264463f;
          u16 x1 = f2bf((row == col ? 2.0f * beta : 0.0f) - beta * beta * p);
          ((u16*)const_cast<void*>(aux))[gi] = x1;
          ((u16*)aux2)[g2] = x1;
          ((u16*)aux2)[g2 + 512] = x1;
        }
      }
    }
  }
}

// 256x256-tile bt-form bf16 MFMA gemm, 256 threads = 4 waves (2Mx2N), BK=64,
// 2 LDS K-tile buffers (128 KiB). Each wave owns a 128x128 output (8x8 16-frags,
// 256 acc VGPRs, 1 wave/SIMD via __launch_bounds__(256,1)). LDS read traffic
// drops to 128K reads + 64K writes per tile = 768 cyc vs 621 MFMA cyc -> 81%
// structural ceiling (8-wave version: 256K -> 60.6%, measured 57.3%).
// Sync structure = round-9 proven class: stage ONLY tile t+1 (issued at tile
// START, maximizing the gap to the wait) into the non-read buffer; one
// vmcnt(0)+s_barrier per tile. Every ds_read has a dependent MFMA before the
// tile-end barrier, so reads drain before any wave crosses it.
// LDS XOR-swizzle byte^=((row&7)<<4) applied both-sides (involution).
// EPI 0: f32 out = acc + aux[col] (bias) ; EPI 2: bf16 C = acc
template<int EPI>
__global__ __launch_bounds__(256, 1) void gemm256(const u16* __restrict__ A, const u16* __restrict__ B,
                                                  void* __restrict__ Cout, const float* __restrict__ aux,
                                                  int M, int N, int K){
  __shared__ __align__(16) char lds[131072];
  const int bz = blockIdx.z;
  const char* Ab = (const char*)(A + (size_t)bz * M * K);
  const char* Bb = (const char*)(B + (size_t)bz * N * K);
  const int NB = N >> 8;
  const int nwg = gridDim.x;
  const int bid = blockIdx.x;
  const int swzb = (bid & 7) * (nwg >> 3) + (bid >> 3);   // nwg % 8 == 0
  const int m0 = (swzb / NB) << 8;
  const int n0 = (swzb % NB) << 8;
  const int tid = threadIdx.x;
  const int w = tid >> 6, l = tid & 63;
  const int wm = w >> 1, wn = w & 1;
  const size_t Kb = (size_t)K << 1;
  const int NT = K >> 6;
  // staging: 256 threads, each line = 32 rows x 128B = 4 KiB; 8 lines per
  // 32 KiB operand half. Source col pre-swizzled by ((row&7)<<4).
  const int sRow = tid >> 3;                               // 0..31
  const int sCol = ((tid & 7) << 4) ^ ((sRow & 7) << 4);
  const int sDst = tid << 4;                               // 0..4095
  const char* aS = Ab + (size_t)(m0 + sRow) * Kb + sCol;
  const char* bS = Bb + (size_t)(n0 + sRow) * Kb + sCol;
  // fragment reads: row = wm*128 + i*16 + (l&15); kbyte = (kk*64 + (l>>4)*16) ^ ((l&7)<<4)
  const int kq0 = (((l >> 4) << 4)) ^ ((l & 7) << 4);
  const int aOff = (wm << 14) + ((l & 15) << 7);
  const int bOff = 32768 + (wn << 14) + ((l & 15) << 7);

  // stage all 8 lines of operand (isB) for K-tile tt into buffer (tt&1)
#define STAGE8(isB, tt) { \
    const int _bo = (((tt) & 1) << 16) + ((isB) << 15); \
    const char* _s = ((isB) ? bS : aS) + ((size_t)(tt) << 7); \
    _Pragma("unroll") for (int L = 0; L < 8; ++L) \
      load16((const u16*)(_s + ((size_t)(L << 5)) * Kb), (u16*)(lds + _bo + (L << 12) + sDst)); }

#define RD_A(dst, bufb, kx) \
  _Pragma("unroll") for (int i = 0; i < 8; ++i) \
    dst[i] = *(const bf16x8*)(lds + (bufb) + aOff + (i << 11) + (kq0 ^ (kx)));
#define RD_B(dst, bufb, kx) \
  _Pragma("unroll") for (int j = 0; j < 8; ++j) \
    dst[j] = *(const bf16x8*)(lds + (bufb) + bOff + (j << 11) + (kq0 ^ (kx)));
#define MFMA64(af, bf) \
  _Pragma("unroll") for (int i = 0; i < 8; ++i) \
    _Pragma("unroll") for (int j = 0; j < 8; ++j) \
      acc[i][j] = __builtin_amdgcn_mfma_f32_16x16x32_bf16(af[i], bf[j], acc[i][j], 0, 0, 0);

#define BAR asm volatile("s_barrier" ::: "memory");
#define VM0 asm volatile("s_waitcnt vmcnt(0)" ::: "memory");

  bf16x8 aF0[8], bF0[8], aF1[8], bF1[8];
  f32x4 acc[8][8] = {};

  // prologue: stage tile 0 fully into buf 0
  STAGE8(0, 0) STAGE8(1, 0)
  VM0 BAR

  // one barrier per K-tile; stages (issued first) target only the non-read buffer
#define KTILE(t, bufb) { \
    if ((t) + 1 < NT) { STAGE8(0, (t)+1) STAGE8(1, (t)+1) } \
    RD_A(aF0, bufb, 0) RD_B(bF0, bufb, 0) \
    RD_A(aF1, bufb, 64) RD_B(bF1, bufb, 64) \
    MFMA64(aF0, bF0) \
    MFMA64(aF1, bF1) \
    __builtin_amdgcn_sched_barrier(0); \
    VM0 BAR }

#pragma unroll 1
  for (int tp = 0; tp < NT; tp += 2){
    KTILE(tp, 0)
    KTILE(tp+1, 65536)
  }
#undef KTILE
#undef STAGE8
#undef RD_A
#undef RD_B
#undef MFMA64
#undef BAR
#undef VM0

#pragma unroll
  for (int i = 0; i < 8; ++i){
    const int row = m0 + (wm << 7) + (i << 4) + ((l >> 4) << 2);
#pragma unroll
    for (int j = 0; j < 8; ++j){
      const int col = n0 + (wn << 7) + (j << 4) + (l & 15);
#pragma unroll
      for (int q = 0; q < 4; ++q){
        float v = acc[i][j][q];
        if (EPI == 0){
          ((float*)Cout)[(size_t)(row + q) * N + col] = v + aux[col];
        } else {
          ((u16*)Cout)[((size_t)bz * M + row + q) * N + col] = f2bf(v);
        }
      }
    }
  }
}

extern "C" void kernel_launch(void* const* d_in, const int* in_sizes, int n_in,
                              void* d_out, int out_size, void* d_ws, size_t ws_size,
                              hipStream_t stream){
  const float* W    = (const float*)d_in[0];
  const float* bias = (const float*)d_in[1];
  const float* x    = (const float*)d_in[2];
  const float* R    = (const float*)d_in[3];
  (void)in_sizes; (void)n_in; (void)out_size; (void)ws_size;

  char* ws = (char*)d_ws;
  const size_t MiB = (size_t)1 << 20;
  u16*   Sbf  = (u16*)(ws + 0 * MiB);    // 4 MiB ; reused as G
  u16*   Dbf  = (u16*)(ws + 4 * MiB);    // 4 MiB
  u16*   X1   = (u16*)(ws + 16 * MiB);   // 4 MiB ; reused as Rbf
  u16*   Ybf  = (u16*)(ws + 20 * MiB);   // 4 MiB ; reused as X3
  u16*   X2   = (u16*)(ws + 24 * MiB);   // 4 MiB
  u16*   Phl  = (u16*)(ws + 28 * MiB);   // 8 MiB  [Ph | Pl] width-1024
  u16*   X2d  = (u16*)(ws + 36 * MiB);   // 8 MiB  [X2 | X2] width-1024
  u16*   X1d  = (u16*)(ws + 44 * MiB);   // 8 MiB  [X1 | X1] width-1024
  u16*   Rbf  = X1;
  u16*   X3   = Ybf;
  u16*   G    = Sbf;
  u16*   Wt   = (u16*)(ws + 8 * MiB);    // 32 MiB [8,40) — NS temps there dead by then
  u16*   filt = (u16*)(ws + 64 * MiB);   // 32 MiB [64,96) — disjoint from xbf
  u16*   xbf  = (u16*)(ws + 0 * MiB);    // 64 MiB [0,64) — everything there dead by then

  const dim3 gNS(4, 4, 8);   // 128x128 tiles, proven gemm_bt

  // Phase 1: S (bf16) and D = (c+1)(cI - S)
  build_s<<<8192, 256, 0, stream>>>(R, Sbf, Dbf);
  // Phase 2: P = c^2 I + S S^T ; fused epilogue emits Phl=[Ph|Pl], X1, X1d
  gemm_bt<11><<<gNS, 256, 0, stream>>>(Sbf, Sbf, Phl, X1, X1d, 512, 512, 512);
  // Phase 3: Y = 2I - (Ph+Pl) X1   (one K=1024 gemm, full-precision P)
  gemm_bt<3><<<gNS, 256, 0, stream>>>(Phl, X1d, Ybf, nullptr, nullptr, 512, 512, 1024);
  // Phase 4: X2 = X1 Y (+ dup into X2d)
  gemm_bt<7><<<gNS, 256, 0, stream>>>(X1, Ybf, X2, X2d, nullptr, 512, 512, 512);
  // Phase 5: R = I - (Ph+Pl) X2   (one K=1024 gemm, bf16 out)
  gemm_bt<10><<<gNS, 256, 0, stream>>>(Phl, X2d, Rbf, nullptr, nullptr, 512, 512, 1024);
  // Phase 6: X3 = X2 + X2 R
  gemm_bt<6><<<gNS, 256, 0, stream>>>(X2, Rbf, X3, X2, nullptr, 512, 512, 512);
  // Phase 7: G = Q = D Pinv - I
  gemm_bt<9><<<gNS, 256, 0, stream>>>(Dbf, X3, G, nullptr, nullptr, 512, 512, 512);
  // Phase 8: filt = G @ Wb (bf16)
  transpose_w<<<dim3(128, 16, 8), 256, 0, stream>>>(W, Wt);
  gemm256<2><<<dim3(32, 1, 8), 256, 0, stream>>>(G, Wt, (void*)filt, nullptr, 512, 4096, 512);
  // Phase 9: x -> bf16
  conv_bf16<<<16384, 256, 0, stream>>>(x, xbf);
  // Phase 10: out = x @ filt^T + bias
  gemm256<0><<<dim3(512, 1, 1), 256, 0, stream>>>(xbf, filt, d_out, bias, 8192, 4096, 4096);
}

// Round 11
// 388.157 us; speedup vs baseline: 1.4320x; 1.4320x over previous
//
#include <hip/hip_runtime.h>

typedef unsigned short u16;
typedef __attribute__((ext_vector_type(8))) short bf16x8;
typedef __attribute__((ext_vector_type(4))) float f32x4;
typedef __attribute__((ext_vector_type(8))) unsigned short u16x8;
typedef __attribute__((ext_vector_type(4))) unsigned short u16x4;

__device__ __forceinline__ u16 f2bf(float f){
  unsigned int u = __builtin_bit_cast(unsigned int, f);
  u += 0x7FFFu + ((u >> 16) & 1u);
  return (u16)(u >> 16);
}
__device__ __forceinline__ float bf2f(u16 h){
  unsigned int u = ((unsigned int)h) << 16;
  return __builtin_bit_cast(float, u);
}

__device__ __forceinline__ void load16(const u16* g, u16* s){
  __builtin_amdgcn_global_load_lds((const __attribute__((address_space(1))) unsigned int*)g,
                                   (__attribute__((address_space(3))) unsigned int*)s,
                                   16, 0, 0);
}

// From R: S = 0.5(A-A^T). Sbf = bf16(S); Dbf = bf16((c+1)(cI - S)), c=1.000001
__global__ __launch_bounds__(256) void build_s(const float* __restrict__ R, u16* __restrict__ Sbf,
                                               u16* __restrict__ Dbf){
  int idx = blockIdx.x * 256 + threadIdx.x;
  int b = idx >> 18;
  int i = (idx >> 9) & 511;
  int j = idx & 511;
  float a  = R[idx];
  float at = R[(b << 18) + (j << 9) + i];
  float s = 0.5f * (a - at);
  Sbf[idx] = f2bf(s);
  Dbf[idx] = f2bf((i == j ? 2.000003f : 0.0f) - 2.000001f * s);
}

// vectorized f32 -> bf16 (8 elems / thread, exact multiple)
__global__ __launch_bounds__(256) void conv_bf16(const float* __restrict__ src, u16* __restrict__ dst){
  size_t i = (size_t)blockIdx.x * 256 + threadIdx.x;
  const float4* s = (const float4*)src + i * 2;
  float4 v0 = s[0], v1 = s[1];
  u16x8 o = { f2bf(v0.x), f2bf(v0.y), f2bf(v0.z), f2bf(v0.w),
              f2bf(v1.x), f2bf(v1.y), f2bf(v1.z), f2bf(v1.w) };
  *(u16x8*)(dst + i * 8) = o;
}

// Wt[b][i][j] = W[b*512 + j][i]  (bf16), i in [0,4096), j in [0,512)
__global__ __launch_bounds__(256) void transpose_w(const float* __restrict__ W, u16* __restrict__ Wt){
  const int b = blockIdx.z;
  const int i0 = blockIdx.x << 5;
  const int j0 = blockIdx.y << 5;
  __shared__ float tile[32][33];
  const int t = threadIdx.x;
  const int r = t >> 3, c = (t & 7) << 2;
  float4 v = *(const float4*)&W[(size_t)((b << 9) + j0 + r) * 4096 + i0 + c];
  tile[r][c+0] = v.x; tile[r][c+1] = v.y; tile[r][c+2] = v.z; tile[r][c+3] = v.w;
  __syncthreads();
  u16x4 o = { f2bf(tile[c+0][r]), f2bf(tile[c+1][r]), f2bf(tile[c+2][r]), f2bf(tile[c+3][r]) };
  *(u16x4*)&Wt[((size_t)b << 21) + (size_t)(i0 + r) * 512 + j0 + c] = o;
}

// 128x64-tile bt-form bf16 MFMA gemm for the small NS steps (256-block grids:
// grid = (N/64, M/128, 8)). 4 waves, each 32 rows x 64 cols (2x4 16x16x32 frags).
// Single-buffered LDS (A 8 KiB + B 4 KiB), __syncthreads staging (deterministic,
// proven class), 4-slot XOR swizzle on the k-byte (both-sides involution:
// LDS[r][slot] = G[r][slot ^ (r&3)], read slot = ((l>>4)^(l&3))&3).
// [Exonerated by round-8 A/B: rounds-7/8 replay failure was gemm256's
// t+2-buffer race, fixed in round 9 — gemm_ns's first-call output was
// bit-identical to gemm_bt's.]
// C is always 512 wide (N=512). K is 512 or 1024 (width of A/B rows).
// EPI 3:  bf16 C = 2*diag - acc
// EPI 6:  bf16 C = bf16(aux_u16[gi]) + acc
// EPI 7:  bf16 C = acc ; also dup into aux (width 1024) at [row][col], [row][col+512]
// EPI 9:  bf16 C = acc - diag
// EPI 10: bf16 C = diag - acc
// EPI 11: p = acc + c^2*diag (f32): Cout(width1024)=[bf16(p)|bf16(p-ph)];
//         x1 = bf16(2b*diag - b^2*p) -> aux (width 512) and aux2 (width 1024, dup)
template<int EPI>
__global__ __launch_bounds__(256) void gemm_ns(const u16* __restrict__ A, const u16* __restrict__ B,
                                               void* __restrict__ Cout, void* __restrict__ aux,
                                               void* __restrict__ aux2,
                                               int M, int N, int K){
  const int bz = blockIdx.z;
  const char* Ab = (const char*)(A + (size_t)bz * M * K);
  const char* Bb = (const char*)(B + (size_t)bz * N * K);
  const int m0 = blockIdx.y << 7, n0 = blockIdx.x << 6;
  __shared__ __align__(16) char As[8192];
  __shared__ __align__(16) char Bs[4096];
  const int t = threadIdx.x;
  const int w = t >> 6, l = t & 63;
  const size_t Kb = (size_t)K << 1;
  const int sR = t >> 2;                       // staging row 0..63
  const int sK = ((t ^ (t >> 2)) & 3) << 4;    // swizzled source k-byte
  const int kq = (((l >> 4) ^ l) & 3) << 4;    // swizzled read k-byte
  const int aRd = ((w << 5) + (l & 15)) * 64 + kq;
  const int bRd = (l & 15) * 64 + kq;
  f32x4 acc[2][4] = {};
  for (int k0 = 0; k0 < K; k0 += 32){
    const size_t kb = (size_t)k0 << 1;
    load16((const u16*)(Ab + (size_t)(m0 + sR) * Kb + kb + sK),      (u16*)(As + t * 16));
    load16((const u16*)(Ab + (size_t)(m0 + 64 + sR) * Kb + kb + sK), (u16*)(As + 4096 + t * 16));
    load16((const u16*)(Bb + (size_t)(n0 + sR) * Kb + kb + sK),      (u16*)(Bs + t * 16));
    __syncthreads();
    bf16x8 aF[2], bF[4];
#pragma unroll
    for (int mf = 0; mf < 2; ++mf) aF[mf] = *(const bf16x8*)(As + aRd + (mf << 10));
#pragma unroll
    for (int nf = 0; nf < 4; ++nf) bF[nf] = *(const bf16x8*)(Bs + bRd + (nf << 10));
#pragma unroll
    for (int mf = 0; mf < 2; ++mf)
#pragma unroll
      for (int nf = 0; nf < 4; ++nf)
        acc[mf][nf] = __builtin_amdgcn_mfma_f32_16x16x32_bf16(aF[mf], bF[nf], acc[mf][nf], 0, 0, 0);
    __syncthreads();
  }
#pragma unroll
  for (int mf = 0; mf < 2; ++mf){
#pragma unroll
    for (int nf = 0; nf < 4; ++nf){
      const int col = n0 + (nf << 4) + (l & 15);
#pragma unroll
      for (int q = 0; q < 4; ++q){
        const int row = m0 + (w << 5) + (mf << 4) + ((l >> 4) << 2) + q;
        float v = acc[mf][nf][q];
        size_t gi = ((size_t)bz * M + row) * N + col;
        size_t g2 = (((size_t)bz * M + row) << 10) + col;
        if (EPI == 3){
          ((u16*)Cout)[gi] = f2bf((row == col ? 2.0f : 0.0f) - v);
        } else if (EPI == 6){
          ((u16*)Cout)[gi] = f2bf(bf2f(((const u16*)aux)[gi]) + v);
        } else if (EPI == 7){
          u16 o = f2bf(v);
          ((u16*)Cout)[gi] = o;
          ((u16*)aux)[g2] = o;
          ((u16*)aux)[g2 + 512] = o;
        } else if (EPI == 9){
          ((u16*)Cout)[gi] = f2bf(v - (row == col ? 1.0f : 0.0f));
        } else if (EPI == 10){
          ((u16*)Cout)[gi] = f2bf((row == col ? 1.0f : 0.0f) - v);
        } else {  // EPI 11: fused P-split + closed-form first NS iterate
          float p = v + (row == col ? 1.000002f : 0.0f);
          u16 ph = f2bf(p);
          ((u16*)Cout)[g2] = ph;
          ((u16*)Cout)[g2 + 512] = f2bf(p - bf2f(ph));
          const float beta = 0.8264463f;
          u16 x1 = f2bf((row == col ? 2.0f * beta : 0.0f) - beta * beta * p);
          ((u16*)aux)[gi] = x1;
          ((u16*)aux2)[g2] = x1;
          ((u16*)aux2)[g2 + 512] = x1;
        }
      }
    }
  }
}

// 256x256-tile bt-form bf16 MFMA gemm — ROUND-9 VERSION VERBATIM (replay-stable,
// 219.8 us @ MfmaUtil 57.3%). 512 threads (8 waves, 2Mx4N), BK=64, 2 LDS K-tile
// buffers (128 KiB). ONE barrier per K-tile; during tile t we stage ONLY tile
// t+1 into buffer (t+1)&1 — never the buffer being read. vmcnt(0) at tile end
// waits on loads issued a full tile earlier. LDS XOR-swizzle byte^=((row&7)<<4)
// both-sides. [Round-10 lesson: 4-wave/256-acc variant (1 wave/SIMD) drops to
// 32.8% — no TLP to hide vmcnt/ds_read latency. 2 waves/SIMD is the operating
// point; do not trade occupancy for LDS-duplication.]
// EPI 0: f32 out = acc + aux[col] (bias) ; EPI 2: bf16 C = acc
template<int EPI>
__global__ __launch_bounds__(512, 2) void gemm256(const u16* __restrict__ A, const u16* __restrict__ B,
                                                  void* __restrict__ Cout, const float* __restrict__ aux,
                                                  int M, int N, int K){
  __shared__ __align__(16) char lds[131072];
  const int bz = blockIdx.z;
  const char* Ab = (const char*)(A + (size_t)bz * M * K);
  const char* Bb = (const char*)(B + (size_t)bz * N * K);
  const int NB = N >> 8;
  const int nwg = gridDim.x;
  const int bid = blockIdx.x;
  const int swzb = (bid & 7) * (nwg >> 3) + (bid >> 3);   // nwg % 8 == 0
  const int m0 = (swzb / NB) << 8;
  const int n0 = (swzb % NB) << 8;
  const int tid = threadIdx.x;
  const int w = tid >> 6, l = tid & 63;
  const int wm = w >> 2, wn = w & 3;
  const size_t Kb = (size_t)K << 1;
  const int NT = K >> 6;
  const int sRow = tid >> 3;
  const int sCol = ((tid & 7) << 4) ^ ((sRow & 7) << 4);
  const int sDst = tid << 4;
  const char* aS = Ab + (size_t)(m0 + sRow) * Kb + sCol;
  const char* bS = Bb + (size_t)(n0 + sRow) * Kb + sCol;
  const int lrow = (l & 15) << 7;
  const int kq0 = (((l >> 4) << 4)) ^ ((l & 7) << 4);
  const int aOff = (wm << 14) + lrow;
  const int bOff = 32768 + ((wn >> 1) << 14) + ((wn & 1) << 13) + lrow;

#define STAGE_H(isB, h, tt) { \
    const int _lo = (((tt) & 1) << 16) + ((isB) << 15) + ((h) << 14); \
    const char* _s = ((isB) ? bS : aS) + ((size_t)((h) << 7)) * Kb + ((size_t)(tt) << 7); \
    load16((const u16*)_s, (u16*)(lds + _lo + sDst)); \
    load16((const u16*)(_s + (Kb << 6)), (u16*)(lds + _lo + 8192 + sDst)); }

#define RD_A(bufb, UQ) \
  _Pragma("unroll") for (int i2 = 0; i2 < 4; ++i2){ \
    aF[i2][0] = *(const bf16x8*)(lds + (bufb) + aOff + ((UQ) << 13) + (i2 << 11) + kq0); \
    aF[i2][1] = *(const bf16x8*)(lds + (bufb) + aOff + ((UQ) << 13) + (i2 << 11) + (kq0 ^ 64)); }

#define RD_B(bufb, VQ) \
  _Pragma("unroll") for (int j2 = 0; j2 < 2; ++j2){ \
    bF[VQ][j2][0] = *(const bf16x8*)(lds + (bufb) + bOff + ((VQ) << 12) + (j2 << 11) + kq0); \
    bF[VQ][j2][1] = *(const bf16x8*)(lds + (bufb) + bOff + ((VQ) << 12) + (j2 << 11) + (kq0 ^ 64)); }

#define MFMA16(UQ, VQ) \
    _Pragma("unroll") for (int i2 = 0; i2 < 4; ++i2) \
      _Pragma("unroll") for (int j2 = 0; j2 < 2; ++j2){ \
        acc[(UQ)*4+i2][(VQ)*2+j2] = __builtin_amdgcn_mfma_f32_16x16x32_bf16(aF[i2][0], bF[VQ][j2][0], acc[(UQ)*4+i2][(VQ)*2+j2], 0, 0, 0); \
        acc[(UQ)*4+i2][(VQ)*2+j2] = __builtin_amdgcn_mfma_f32_16x16x32_bf16(aF[i2][1], bF[VQ][j2][1], acc[(UQ)*4+i2][(VQ)*2+j2], 0, 0, 0); }

#define BAR asm volatile("s_barrier" ::: "memory");
#define VM0 asm volatile("s_waitcnt vmcnt(0)" ::: "memory");

  bf16x8 aF[4][2], bF[2][2][2];
  f32x4 acc[8][4] = {};

  // prologue: stage tile 0 fully into buf 0
  STAGE_H(0,0,0) STAGE_H(1,0,0) STAGE_H(0,1,0) STAGE_H(1,1,0)
  VM0 BAR

  // one barrier per K-tile; stages target only the non-read buffer
#define KTILE(t, bufb) { \
    RD_A(bufb, 0) RD_B(bufb, 0) \
    if ((t) + 1 < NT) { STAGE_H(0,0,(t)+1) STAGE_H(1,0,(t)+1) } \
    MFMA16(0,0) \
    RD_B(bufb, 1) \
    if ((t) + 1 < NT) { STAGE_H(0,1,(t)+1) STAGE_H(1,1,(t)+1) } \
    MFMA16(0,1) \
    RD_A(bufb, 1) \
    MFMA16(1,1) \
    MFMA16(1,0) \
    __builtin_amdgcn_sched_barrier(0); \
    VM0 BAR }

#pragma unroll 1
  for (int tp = 0; tp < NT; tp += 2){
    KTILE(tp, 0)
    KTILE(tp+1, 65536)
  }
#undef KTILE
#undef STAGE_H
#undef RD_A
#undef RD_B
#undef MFMA16
#undef BAR
#undef VM0

#pragma unroll
  for (int mf = 0; mf < 8; ++mf){
#pragma unroll
    for (int nf = 0; nf < 4; ++nf){
      const int col = n0 + (wn << 6) + (nf << 4) + (l & 15);
#pragma unroll
      for (int q = 0; q < 4; ++q){
        const int row = m0 + (wm << 7) + (mf << 4) + ((l >> 4) << 2) + q;
        float v = acc[mf][nf][q];
        if (EPI == 0){
          ((float*)Cout)[(size_t)row * N + col] = v + aux[col];
        } else {
          ((u16*)Cout)[((size_t)bz * M + row) * N + col] = f2bf(v);
        }
      }
    }
  }
}

extern "C" void kernel_launch(void* const* d_in, const int* in_sizes, int n_in,
                              void* d_out, int out_size, void* d_ws, size_t ws_size,
                              hipStream_t stream){
  const float* W    = (const float*)d_in[0];
  const float* bias = (const float*)d_in[1];
  const float* x    = (const float*)d_in[2];
  const float* R    = (const float*)d_in[3];
  (void)in_sizes; (void)n_in; (void)out_size; (void)ws_size;

  char* ws = (char*)d_ws;
  const size_t MiB = (size_t)1 << 20;
  u16*   Sbf  = (u16*)(ws + 0 * MiB);    // 4 MiB ; reused as G
  u16*   Dbf  = (u16*)(ws + 4 * MiB);    // 4 MiB
  u16*   X1   = (u16*)(ws + 16 * MiB);   // 4 MiB ; reused as Rbf
  u16*   Ybf  = (u16*)(ws + 20 * MiB);   // 4 MiB ; reused as X3
  u16*   X2   = (u16*)(ws + 24 * MiB);   // 4 MiB
  u16*   Phl  = (u16*)(ws + 28 * MiB);   // 8 MiB  [Ph | Pl] width-1024
  u16*   X2d  = (u16*)(ws + 36 * MiB);   // 8 MiB  [X2 | X2] width-1024
  u16*   X1d  = (u16*)(ws + 44 * MiB);   // 8 MiB  [X1 | X1] width-1024
  u16*   Rbf  = X1;
  u16*   X3   = Ybf;
  u16*   G    = Sbf;
  u16*   Wt   = (u16*)(ws + 8 * MiB);    // 32 MiB [8,40) — NS temps there dead by then
  u16*   filt = (u16*)(ws + 64 * MiB);   // 32 MiB [64,96) — disjoint from xbf
  u16*   xbf  = (u16*)(ws + 0 * MiB);    // 64 MiB [0,64) — everything there dead by then

  const dim3 gNS(8, 4, 8);   // 256 blocks: 128x64 tiles (gemm_ns)

  // Phase 1: S (bf16) and D = (c+1)(cI - S)
  build_s<<<8192, 256, 0, stream>>>(R, Sbf, Dbf);
  // Phase 2: P = c^2 I + S S^T ; fused epilogue emits Phl=[Ph|Pl], X1, X1d
  gemm_ns<11><<<gNS, 256, 0, stream>>>(Sbf, Sbf, Phl, X1, X1d, 512, 512, 512);
  // Phase 3: Y = 2I - (Ph+Pl) X1   (one K=1024 gemm, full-precision P)
  gemm_ns<3><<<gNS, 256, 0, stream>>>(Phl, X1d, Ybf, nullptr, nullptr, 512, 512, 1024);
  // Phase 4: X2 = X1 Y (+ dup into X2d)
  gemm_ns<7><<<gNS, 256, 0, stream>>>(X1, Ybf, X2, X2d, nullptr, 512, 512, 512);
  // Phase 5: R = I - (Ph+Pl) X2   (one K=1024 gemm, bf16 out)
  gemm_ns<10><<<gNS, 256, 0, stream>>>(Phl, X2d, Rbf, nullptr, nullptr, 512, 512, 1024);
  // Phase 6: X3 = X2 + X2 R
  gemm_ns<6><<<gNS, 256, 0, stream>>>(X2, Rbf, X3, X2, nullptr, 512, 512, 512);
  // Phase 7: G = Q = D Pinv - I
  gemm_ns<9><<<gNS, 256, 0, stream>>>(Dbf, X3, G, nullptr, nullptr, 512, 512, 512);
  // Phase 8: filt = G @ Wb (bf16)
  transpose_w<<<dim3(128, 16, 8), 256, 0, stream>>>(W, Wt);
  gemm256<2><<<dim3(32, 1, 8), 512, 0, stream>>>(G, Wt, (void*)filt, nullptr, 512, 4096, 512);
  // Phase 9: x -> bf16
  conv_bf16<<<16384, 256, 0, stream>>>(x, xbf);
  // Phase 10: out = x @ filt^T + bias
  gemm256<0><<<dim3(512, 1, 1), 512, 0, stream>>>(xbf, filt, d_out, bias, 8192, 4096, 4096);
}

// Round 12
// 346.553 us; speedup vs baseline: 1.6039x; 1.1201x over previous
//
#include <hip/hip_runtime.h>

typedef unsigned short u16;
typedef __attribute__((ext_vector_type(8))) short bf16x8;
typedef __attribute__((ext_vector_type(4))) float f32x4;
typedef __attribute__((ext_vector_type(8))) unsigned short u16x8;
typedef __attribute__((ext_vector_type(4))) unsigned short u16x4;

__device__ __forceinline__ u16 f2bf(float f){
  unsigned int u = __builtin_bit_cast(unsigned int, f);
  u += 0x7FFFu + ((u >> 16) & 1u);
  return (u16)(u >> 16);
}
__device__ __forceinline__ float bf2f(u16 h){
  unsigned int u = ((unsigned int)h) << 16;
  return __builtin_bit_cast(float, u);
}

__device__ __forceinline__ void load16(const u16* g, u16* s){
  __builtin_amdgcn_global_load_lds((const __attribute__((address_space(1))) unsigned int*)g,
                                   (__attribute__((address_space(3))) unsigned int*)s,
                                   16, 0, 0);
}

// From R: S = 0.5(A-A^T). Sbf = bf16(S); Dbf = bf16((c+1)(cI - S)), c=1.000001
__global__ __launch_bounds__(256) void build_s(const float* __restrict__ R, u16* __restrict__ Sbf,
                                               u16* __restrict__ Dbf){
  int idx = blockIdx.x * 256 + threadIdx.x;
  int b = idx >> 18;
  int i = (idx >> 9) & 511;
  int j = idx & 511;
  float a  = R[idx];
  float at = R[(b << 18) + (j << 9) + i];
  float s = 0.5f * (a - at);
  Sbf[idx] = f2bf(s);
  Dbf[idx] = f2bf((i == j ? 2.000003f : 0.0f) - 2.000001f * s);
}

// vectorized f32 -> bf16 (8 elems / thread, exact multiple)
__global__ __launch_bounds__(256) void conv_bf16(const float* __restrict__ src, u16* __restrict__ dst){
  size_t i = (size_t)blockIdx.x * 256 + threadIdx.x;
  const float4* s = (const float4*)src + i * 2;
  float4 v0 = s[0], v1 = s[1];
  u16x8 o = { f2bf(v0.x), f2bf(v0.y), f2bf(v0.z), f2bf(v0.w),
              f2bf(v1.x), f2bf(v1.y), f2bf(v1.z), f2bf(v1.w) };
  *(u16x8*)(dst + i * 8) = o;
}

// Wt[b][i][j] = W[b*512 + j][i]  (bf16), i in [0,4096), j in [0,512)
__global__ __launch_bounds__(256) void transpose_w(const float* __restrict__ W, u16* __restrict__ Wt){
  const int b = blockIdx.z;
  const int i0 = blockIdx.x << 5;
  const int j0 = blockIdx.y << 5;
  __shared__ float tile[32][33];
  const int t = threadIdx.x;
  const int r = t >> 3, c = (t & 7) << 2;
  float4 v = *(const float4*)&W[(size_t)((b << 9) + j0 + r) * 4096 + i0 + c];
  tile[r][c+0] = v.x; tile[r][c+1] = v.y; tile[r][c+2] = v.z; tile[r][c+3] = v.w;
  __syncthreads();
  u16x4 o = { f2bf(tile[c+0][r]), f2bf(tile[c+1][r]), f2bf(tile[c+2][r]), f2bf(tile[c+3][r]) };
  *(u16x4*)&Wt[((size_t)b << 21) + (size_t)(i0 + r) * 512 + j0 + c] = o;
}

// 64x64-tile bt-form bf16 MFMA gemm for the small NS steps: grid (N/64, M/64, 8)
// = 512 blocks (2 blocks/CU -> one block's staging latency hides under the
// other's compute; round-11 128x64 version ran 256 blocks = 1/CU, latency-serial).
// 4 waves (2Mx2N), each 32x32 output (2x2 16x16x32 frags). Single-buffered LDS
// (A 4 KiB + B 4 KiB), __syncthreads staging (deterministic class), 4-slot XOR
// swizzle on the k-byte: LDS[r][slot] = G[r][slot ^ (r&3)], read slot ((l>>4)^l)&3.
// C is always 512 wide (N=512). K is 512 or 1024 (width of A/B rows).
// EPI 2:  bf16 C = acc
// EPI 3:  bf16 C = 2*diag - acc
// EPI 9:  bf16 C = acc - diag
// EPI 11: p = acc + c^2*diag (f32): Cout(width1024)=[bf16(p)|bf16(p-ph)];
//         x1 = bf16(2b*diag - b^2*p) -> aux (width 512) and aux2 (width 1024, dup)
template<int EPI>
__global__ __launch_bounds__(256) void gemm_ns(const u16* __restrict__ A, const u16* __restrict__ B,
                                               void* __restrict__ Cout, void* __restrict__ aux,
                                               void* __restrict__ aux2,
                                               int M, int N, int K){
  const int bz = blockIdx.z;
  const char* Ab = (const char*)(A + (size_t)bz * M * K);
  const char* Bb = (const char*)(B + (size_t)bz * N * K);
  const int m0 = blockIdx.y << 6, n0 = blockIdx.x << 6;
  __shared__ __align__(16) char As[4096];
  __shared__ __align__(16) char Bs[4096];
  const int t = threadIdx.x;
  const int w = t >> 6, l = t & 63;
  const int wm = w >> 1, wn = w & 1;
  const size_t Kb = (size_t)K << 1;
  const int sR = t >> 2;                       // staging row 0..63 (1 line/thread)
  const int sK = ((t ^ (t >> 2)) & 3) << 4;    // swizzled source k-byte
  const int kq = (((l >> 4) ^ l) & 3) << 4;    // swizzled read k-byte
  const int aRd = ((wm << 5) + (l & 15)) * 64 + kq;
  const int bRd = ((wn << 5) + (l & 15)) * 64 + kq;
  f32x4 acc[2][2] = {};
  for (int k0 = 0; k0 < K; k0 += 32){
    const size_t kb = (size_t)k0 << 1;
    load16((const u16*)(Ab + (size_t)(m0 + sR) * Kb + kb + sK), (u16*)(As + t * 16));
    load16((const u16*)(Bb + (size_t)(n0 + sR) * Kb + kb + sK), (u16*)(Bs + t * 16));
    __syncthreads();
    bf16x8 aF[2], bF[2];
#pragma unroll
    for (int mf = 0; mf < 2; ++mf) aF[mf] = *(const bf16x8*)(As + aRd + (mf << 10));
#pragma unroll
    for (int nf = 0; nf < 2; ++nf) bF[nf] = *(const bf16x8*)(Bs + bRd + (nf << 10));
#pragma unroll
    for (int mf = 0; mf < 2; ++mf)
#pragma unroll
      for (int nf = 0; nf < 2; ++nf)
        acc[mf][nf] = __builtin_amdgcn_mfma_f32_16x16x32_bf16(aF[mf], bF[nf], acc[mf][nf], 0, 0, 0);
    __syncthreads();
  }
#pragma unroll
  for (int mf = 0; mf < 2; ++mf){
#pragma unroll
    for (int nf = 0; nf < 2; ++nf){
      const int col = n0 + (wn << 5) + (nf << 4) + (l & 15);
#pragma unroll
      for (int q = 0; q < 4; ++q){
        const int row = m0 + (wm << 5) + (mf << 4) + ((l >> 4) << 2) + q;
        float v = acc[mf][nf][q];
        size_t gi = ((size_t)bz * M + row) * N + col;
        size_t g2 = (((size_t)bz * M + row) << 10) + col;
        if (EPI == 2){
          ((u16*)Cout)[gi] = f2bf(v);
        } else if (EPI == 3){
          ((u16*)Cout)[gi] = f2bf((row == col ? 2.0f : 0.0f) - v);
        } else if (EPI == 9){
          ((u16*)Cout)[gi] = f2bf(v - (row == col ? 1.0f : 0.0f));
        } else {  // EPI 11: fused P-split + closed-form first NS iterate
          float p = v + (row == col ? 1.000002f : 0.0f);
          u16 ph = f2bf(p);
          ((u16*)Cout)[g2] = ph;
          ((u16*)Cout)[g2 + 512] = f2bf(p - bf2f(ph));
          const float beta = 0.8264463f;
          u16 x1 = f2bf((row == col ? 2.0f * beta : 0.0f) - beta * beta * p);
          ((u16*)aux)[gi] = x1;
          ((u16*)aux2)[g2] = x1;
          ((u16*)aux2)[g2 + 512] = x1;
        }
      }
    }
  }
}

// 256x256-tile bt-form bf16 MFMA gemm — ROUND-9 VERSION VERBATIM (replay-stable,
// 219.8 us @ MfmaUtil 57.3% = ~95% of the 8-wave structure's LDS-traffic ceiling).
// 512 threads (8 waves, 2Mx4N), BK=64, 2 LDS K-tile buffers (128 KiB). ONE
// barrier per K-tile; during tile t we stage ONLY tile t+1 into buffer (t+1)&1
// — never the buffer being read. vmcnt(0) at tile end waits on loads issued a
// full tile earlier. LDS XOR-swizzle byte^=((row&7)<<4) both-sides.
// [Round-10 lesson: 4-wave/256-acc (1 wave/SIMD) drops to 32.8% — no TLP to
// hide latency. 2 waves/SIMD is the operating point.]
// EPI 0: f32 out = acc + aux[col] (bias) ; EPI 2: bf16 C = acc
template<int EPI>
__global__ __launch_bounds__(512, 2) void gemm256(const u16* __restrict__ A, const u16* __restrict__ B,
                                                  void* __restrict__ Cout, const float* __restrict__ aux,
                                                  int M, int N, int K){
  __shared__ __align__(16) char lds[131072];
  const int bz = blockIdx.z;
  const char* Ab = (const char*)(A + (size_t)bz * M * K);
  const char* Bb = (const char*)(B + (size_t)bz * N * K);
  const int NB = N >> 8;
  const int nwg = gridDim.x;
  const int bid = blockIdx.x;
  const int swzb = (bid & 7) * (nwg >> 3) + (bid >> 3);   // nwg % 8 == 0
  const int m0 = (swzb / NB) << 8;
  const int n0 = (swzb % NB) << 8;
  const int tid = threadIdx.x;
  const int w = tid >> 6, l = tid & 63;
  const int wm = w >> 2, wn = w & 3;
  const size_t Kb = (size_t)K << 1;
  const int NT = K >> 6;
  const int sRow = tid >> 3;
  const int sCol = ((tid & 7) << 4) ^ ((sRow & 7) << 4);
  const int sDst = tid << 4;
  const char* aS = Ab + (size_t)(m0 + sRow) * Kb + sCol;
  const char* bS = Bb + (size_t)(n0 + sRow) * Kb + sCol;
  const int lrow = (l & 15) << 7;
  const int kq0 = (((l >> 4) << 4)) ^ ((l & 7) << 4);
  const int aOff = (wm << 14) + lrow;
  const int bOff = 32768 + ((wn >> 1) << 14) + ((wn & 1) << 13) + lrow;

#define STAGE_H(isB, h, tt) { \
    const int _lo = (((tt) & 1) << 16) + ((isB) << 15) + ((h) << 14); \
    const char* _s = ((isB) ? bS : aS) + ((size_t)((h) << 7)) * Kb + ((size_t)(tt) << 7); \
    load16((const u16*)_s, (u16*)(lds + _lo + sDst)); \
    load16((const u16*)(_s + (Kb << 6)), (u16*)(lds + _lo + 8192 + sDst)); }

#define RD_A(bufb, UQ) \
  _Pragma("unroll") for (int i2 = 0; i2 < 4; ++i2){ \
    aF[i2][0] = *(const bf16x8*)(lds + (bufb) + aOff + ((UQ) << 13) + (i2 << 11) + kq0); \
    aF[i2][1] = *(const bf16x8*)(lds + (bufb) + aOff + ((UQ) << 13) + (i2 << 11) + (kq0 ^ 64)); }

#define RD_B(bufb, VQ) \
  _Pragma("unroll") for (int j2 = 0; j2 < 2; ++j2){ \
    bF[VQ][j2][0] = *(const bf16x8*)(lds + (bufb) + bOff + ((VQ) << 12) + (j2 << 11) + kq0); \
    bF[VQ][j2][1] = *(const bf16x8*)(lds + (bufb) + bOff + ((VQ) << 12) + (j2 << 11) + (kq0 ^ 64)); }

#define MFMA16(UQ, VQ) \
    _Pragma("unroll") for (int i2 = 0; i2 < 4; ++i2) \
      _Pragma("unroll") for (int j2 = 0; j2 < 2; ++j2){ \
        acc[(UQ)*4+i2][(VQ)*2+j2] = __builtin_amdgcn_mfma_f32_16x16x32_bf16(aF[i2][0], bF[VQ][j2][0], acc[(UQ)*4+i2][(VQ)*2+j2], 0, 0, 0); \
        acc[(UQ)*4+i2][(VQ)*2+j2] = __builtin_amdgcn_mfma_f32_16x16x32_bf16(aF[i2][1], bF[VQ][j2][1], acc[(UQ)*4+i2][(VQ)*2+j2], 0, 0, 0); }

#define BAR asm volatile("s_barrier" ::: "memory");
#define VM0 asm volatile("s_waitcnt vmcnt(0)" ::: "memory");

  bf16x8 aF[4][2], bF[2][2][2];
  f32x4 acc[8][4] = {};

  // prologue: stage tile 0 fully into buf 0
  STAGE_H(0,0,0) STAGE_H(1,0,0) STAGE_H(0,1,0) STAGE_H(1,1,0)
  VM0 BAR

  // one barrier per K-tile; stages target only the non-read buffer
#define KTILE(t, bufb) { \
    RD_A(bufb, 0) RD_B(bufb, 0) \
    if ((t) + 1 < NT) { STAGE_H(0,0,(t)+1) STAGE_H(1,0,(t)+1) } \
    MFMA16(0,0) \
    RD_B(bufb, 1) \
    if ((t) + 1 < NT) { STAGE_H(0,1,(t)+1) STAGE_H(1,1,(t)+1) } \
    MFMA16(0,1) \
    RD_A(bufb, 1) \
    MFMA16(1,1) \
    MFMA16(1,0) \
    __builtin_amdgcn_sched_barrier(0); \
    VM0 BAR }

#pragma unroll 1
  for (int tp = 0; tp < NT; tp += 2){
    KTILE(tp, 0)
    KTILE(tp+1, 65536)
  }
#undef KTILE
#undef STAGE_H
#undef RD_A
#undef RD_B
#undef MFMA16
#undef BAR
#undef VM0

#pragma unroll
  for (int mf = 0; mf < 8; ++mf){
#pragma unroll
    for (int nf = 0; nf < 4; ++nf){
      const int col = n0 + (wn << 6) + (nf << 4) + (l & 15);
#pragma unroll
      for (int q = 0; q < 4; ++q){
        const int row = m0 + (wm << 7) + (mf << 4) + ((l >> 4) << 2) + q;
        float v = acc[mf][nf][q];
        if (EPI == 0){
          ((float*)Cout)[(size_t)row * N + col] = v + aux[col];
        } else {
          ((u16*)Cout)[((size_t)bz * M + row) * N + col] = f2bf(v);
        }
      }
    }
  }
}

extern "C" void kernel_launch(void* const* d_in, const int* in_sizes, int n_in,
                              void* d_out, int out_size, void* d_ws, size_t ws_size,
                              hipStream_t stream){
  const float* W    = (const float*)d_in[0];
  const float* bias = (const float*)d_in[1];
  const float* x    = (const float*)d_in[2];
  const float* R    = (const float*)d_in[3];
  (void)in_sizes; (void)n_in; (void)out_size; (void)ws_size;

  char* ws = (char*)d_ws;
  const size_t MiB = (size_t)1 << 20;
  u16*   Sbf  = (u16*)(ws + 0 * MiB);    // 4 MiB ; reused as G
  u16*   Dbf  = (u16*)(ws + 4 * MiB);    // 4 MiB
  u16*   X1   = (u16*)(ws + 16 * MiB);   // 4 MiB
  u16*   Ybf  = (u16*)(ws + 20 * MiB);   // 4 MiB
  u16*   X2   = (u16*)(ws + 24 * MiB);   // 4 MiB
  u16*   Phl  = (u16*)(ws + 28 * MiB);   // 8 MiB  [Ph | Pl] width-1024
  u16*   X1d  = (u16*)(ws + 44 * MiB);   // 8 MiB  [X1 | X1] width-1024
  u16*   G    = Sbf;
  u16*   Wt   = (u16*)(ws + 8 * MiB);    // 32 MiB [8,40) — NS temps there dead by then
  u16*   filt = (u16*)(ws + 64 * MiB);   // 32 MiB [64,96) — disjoint from xbf
  u16*   xbf  = (u16*)(ws + 0 * MiB);    // 64 MiB [0,64) — everything there dead by then

  const dim3 gNS(8, 8, 8);   // 512 blocks: 64x64 tiles, 2 blocks/CU (gemm_ns)

  // Phase 1: S (bf16) and D = (c+1)(cI - S)
  build_s<<<8192, 256, 0, stream>>>(R, Sbf, Dbf);
  // Phase 2: P = c^2 I + S S^T ; fused epilogue emits Phl=[Ph|Pl], X1, X1d
  gemm_ns<11><<<gNS, 256, 0, stream>>>(Sbf, Sbf, Phl, X1, X1d, 512, 512, 512);
  // Phase 3: Y = 2I - (Ph+Pl) X1   (one K=1024 gemm, full-precision P)
  gemm_ns<3><<<gNS, 256, 0, stream>>>(Phl, X1d, Ybf, nullptr, nullptr, 512, 512, 1024);
  // Phase 4: X2 = X1 Y  (refinement dropped: residual e1^2 ~ 9e-4 + P-rounding
  //          ~3e-3 contribute ~0.012 to out, below the 0.047 bf16 floor)
  gemm_ns<2><<<gNS, 256, 0, stream>>>(X1, Ybf, X2, nullptr, nullptr, 512, 512, 512);
  // Phase 5: G = Q = D X2 - I
  gemm_ns<9><<<gNS, 256, 0, stream>>>(Dbf, X2, G, nullptr, nullptr, 512, 512, 512);
  // Phase 6: filt = G @ Wb (bf16)
  transpose_w<<<dim3(128, 16, 8), 256, 0, stream>>>(W, Wt);
  gemm256<2><<<dim3(32, 1, 8), 512, 0, stream>>>(G, Wt, (void*)filt, nullptr, 512, 4096, 512);
  // Phase 7: x -> bf16
  conv_bf16<<<16384, 256, 0, stream>>>(x, xbf);
  // Phase 8: out = x @ filt^T + bias
  gemm256<0><<<dim3(512, 1, 1), 512, 0, stream>>>(xbf, filt, d_out, bias, 8192, 4096, 4096);
}